// Round 1
// baseline (1056.281 us; speedup 1.0000x reference)
//
#include <hip/hip_runtime.h>
#include <hip/hip_bf16.h>
#include <math.h>

#define B_ROWS 4096
#define E_EDGES 131072
#define DZ 256
#define DPAIR 256
#define HD4 3072      // 4*D_LM
#define NOUT 12288    // M_PREFIX*D_LM

typedef short bf16x8 __attribute__((ext_vector_type(8)));
typedef float f32x4 __attribute__((ext_vector_type(4)));

__device__ __forceinline__ void gload_lds16(const void* g, void* l) {
  __builtin_amdgcn_global_load_lds(
      (const __attribute__((address_space(1))) unsigned int*)g,
      (__attribute__((address_space(3))) unsigned int*)l, 16, 0, 0);
}

// ---------------- W_qu = Wv^T @ Wu  [256,256] ----------------
__global__ __launch_bounds__(256) void wqu_kernel(const float* __restrict__ Wv,
                                                  const float* __restrict__ Wu,
                                                  float* __restrict__ Wqu) {
  int d = blockIdx.x, dp = threadIdx.x;
  __shared__ float col[256];
  col[dp] = Wv[dp * 256 + d];          // column d of Wv
  __syncthreads();
  float acc = 0.f;
#pragma unroll 8
  for (int h = 0; h < 256; ++h)
    acc += col[h] * Wu[h * 256 + dp];
  Wqu[d * 256 + dp] = acc;
}

// ---------------- u = Z_self @ W_qu  [B,256], 16 rows/block ----------------
__global__ __launch_bounds__(256) void u_kernel(const float* __restrict__ Zs,
                                                const float* __restrict__ Wqu,
                                                float* __restrict__ u) {
  __shared__ float z[16][256];
  int tid = threadIdx.x;
  int r0 = blockIdx.x * 16;
#pragma unroll
  for (int r = 0; r < 16; ++r)
    z[r][tid] = Zs[(size_t)(r0 + r) * 256 + tid];
  __syncthreads();
  float acc[16] = {};
  for (int k = 0; k < 256; ++k) {
    float wv = Wqu[k * 256 + tid];
#pragma unroll
    for (int r = 0; r < 16; ++r) acc[r] += z[r][k] * wv;
  }
#pragma unroll
  for (int r = 0; r < 16; ++r)
    u[(size_t)(r0 + r) * 256 + tid] = acc[r];
}

// ---------------- f32 -> bf16 conversion (vectorized) ----------------
__global__ void cvt_bf16(const float4* __restrict__ in, ushort4* __restrict__ out, int n4) {
  int i = blockIdx.x * 256 + threadIdx.x;
  if (i >= n4) return;
  float4 v = in[i];
  union { __hip_bfloat16 h[4]; ushort4 u; } o;
  o.h[0] = __float2bfloat16(v.x);
  o.h[1] = __float2bfloat16(v.y);
  o.h[2] = __float2bfloat16(v.z);
  o.h[3] = __float2bfloat16(v.w);
  out[i] = o.u;
}

// ------- per-segment attention softmax + weighted aggregation -------
// block b handles edges [ptr[b], ptr[b+1]); e_i = z_i . u_b / 16
__global__ __launch_bounds__(256) void attn_agg(const float* __restrict__ Zn,
                                                const float* __restrict__ Ep,
                                                const float* __restrict__ u,
                                                const int* __restrict__ ptr,
                                                float* __restrict__ e_ws,
                                                __hip_bfloat16* __restrict__ EvX) {
  int b = blockIdx.x;
  int tid = threadIdx.x;
  int lane = tid & 63, w = tid >> 6;
  int s = ptr[b], t = ptr[b + 1];
  int cnt = t - s;
  __shared__ float u_lds[256];
  __shared__ float ebuf[2048];
  __shared__ float wmax[4];
  u_lds[tid] = u[(size_t)b * 256 + tid];
  __syncthreads();
  float* est = (cnt <= 2048) ? ebuf : (e_ws + s);
  float wm = -INFINITY;
  for (int i = s + w; i < t; i += 4) {           // one edge per wave
    const float* zr = Zn + (size_t)i * 256;
    float p = zr[lane]       * u_lds[lane]
            + zr[lane + 64]  * u_lds[lane + 64]
            + zr[lane + 128] * u_lds[lane + 128]
            + zr[lane + 192] * u_lds[lane + 192];
#pragma unroll
    for (int off = 32; off; off >>= 1) p += __shfl_xor(p, off);
    float e = p * 0.0625f;                       // / sqrt(256)
    if (lane == 0) est[i - s] = e;
    wm = fmaxf(wm, e);
  }
  if (lane == 0) wmax[w] = wm;
  __syncthreads();
  if (cnt > 0) {
    float mx = fmaxf(fmaxf(wmax[0], wmax[1]), fmaxf(wmax[2], wmax[3]));
    float ssum = 0.f, acc = 0.f;
    for (int i = s; i < t; ++i) {
      float ex = __expf(est[i - s] - mx);        // broadcast read
      ssum += ex;
      acc += ex * Ep[(size_t)i * 256 + tid];     // coalesced
    }
    EvX[(size_t)b * 256 + tid] = __float2bfloat16(acc / ssum);
  } else {
    EvX[(size_t)b * 256 + tid] = __float2bfloat16(0.f);   // empty segment -> 0
  }
}

// ---------------- bf16 MFMA GEMM, C = A @ Bw^T (+bias [+gelu]) ----------------
// A [M,K] bf16 row-major, Bw [N,K] bf16 row-major (torch weight layout).
// m97 structure: 128x128 tile, BK=32, 4 waves (2x2), global_load_lds w=16.
// EPI==0: f32 out + bias.  EPI==1: bf16 out + bias + exact-erf gelu.
template <int EPI>
__global__ __launch_bounds__(256) void gemm_bt(const ushort* __restrict__ A,
                                               const ushort* __restrict__ Bw,
                                               const float* __restrict__ bias,
                                               void* __restrict__ Cout,
                                               int M, int N, int K) {
  constexpr int BM = 128, BN = 128, BK = 32;
  __shared__ __align__(16) ushort As[BM * BK];
  __shared__ __align__(16) ushort Bs[BN * BK];
  int tid = threadIdx.x;
  int lane = tid & 63;
  int w = tid >> 6;
  int wr = w >> 1, wc = w & 1;

  // XCD-aware bijective swizzle (grid % 8 == 0 for all our launches)
  int nbx = N / BN;
  int nwg = gridDim.x;
  int bid = blockIdx.x;
  int cpx = nwg >> 3;
  int swz = (bid & 7) * cpx + (bid >> 3);
  int bn = (swz % nbx) * BN;
  int bm = (swz / nbx) * BM;

  const ushort* Abase = A + (size_t)bm * K;
  const ushort* Bbase = Bw + (size_t)bn * K;

  f32x4 acc[4][4] = {};
  int r0 = lane & 15;
  int k0 = (lane >> 4) * 8;

  for (int kt = 0; kt < K; kt += BK) {
    // stage 128x32 A-tile and B-tile (512 x 16B chunks each; 2 per thread)
#pragma unroll
    for (int j = 0; j < 2; ++j) {
      int c = j * 256 + tid;
      int row = c >> 2, col = (c & 3) * 8;
      gload_lds16(Abase + (size_t)row * K + kt + col,
                  (char*)As + (j * 256 + w * 64) * 16);
      gload_lds16(Bbase + (size_t)row * K + kt + col,
                  (char*)Bs + (j * 256 + w * 64) * 16);
    }
    __syncthreads();   // compiler drains vmcnt before s_barrier
    bf16x8 af[4], bf[4];
#pragma unroll
    for (int m = 0; m < 4; ++m)
      af[m] = *(const bf16x8*)&As[(wr * 64 + m * 16 + r0) * BK + k0];
#pragma unroll
    for (int n = 0; n < 4; ++n)
      bf[n] = *(const bf16x8*)&Bs[(wc * 64 + n * 16 + r0) * BK + k0];
#pragma unroll
    for (int m = 0; m < 4; ++m)
#pragma unroll
      for (int n = 0; n < 4; ++n)
        acc[m][n] = __builtin_amdgcn_mfma_f32_16x16x32_bf16(af[m], bf[n], acc[m][n], 0, 0, 0);
    __syncthreads();
  }

  // epilogue; C/D layout: col = lane&15, row = (lane>>4)*4 + reg
  int rg = (lane >> 4) * 4;
#pragma unroll
  for (int n = 0; n < 4; ++n) {
    int col = bn + wc * 64 + n * 16 + r0;
    float bv = bias[col];
#pragma unroll
    for (int m = 0; m < 4; ++m) {
      int rowb = bm + wr * 64 + m * 16 + rg;
#pragma unroll
      for (int r = 0; r < 4; ++r) {
        float x = acc[m][n][r] + bv;
        if (EPI == 1) {
          float g = 0.5f * x * (1.0f + erff(x * 0.70710678118654752f));
          ((__hip_bfloat16*)Cout)[(size_t)(rowb + r) * N + col] = __float2bfloat16(g);
        } else {
          ((float*)Cout)[(size_t)(rowb + r) * N + col] = x;
        }
      }
    }
  }
}

extern "C" void kernel_launch(void* const* d_in, const int* in_sizes, int n_in,
                              void* d_out, int out_size, void* d_ws, size_t ws_size,
                              hipStream_t stream) {
  const float* Zs = (const float*)d_in[0];
  const float* Zn = (const float*)d_in[1];
  const float* Ep = (const float*)d_in[2];
  const float* Wv = (const float*)d_in[3];
  const float* Wu = (const float*)d_in[4];
  const float* W1 = (const float*)d_in[5];
  const float* b1 = (const float*)d_in[6];
  const float* W2 = (const float*)d_in[7];
  const float* b2 = (const float*)d_in[8];
  const int* ptr  = (const int*)d_in[9];
  float* out = (float*)d_out;

  char* ws = (char*)d_ws;
  size_t off = 0;
  auto alloc = [&](size_t bytes) {
    void* p = ws + off;
    off = (off + bytes + 255) & ~(size_t)255;
    return p;
  };
  ushort* W2b  = (ushort*)alloc((size_t)NOUT * HD4 * 2);      // 75.5 MB
  ushort* W1b  = (ushort*)alloc((size_t)HD4 * DPAIR * 2);     // 1.6 MB
  ushort* hdn  = (ushort*)alloc((size_t)B_ROWS * HD4 * 2);    // 25.2 MB
  ushort* EvXb = (ushort*)alloc((size_t)B_ROWS * DPAIR * 2);  // 2.1 MB
  float*  u_ws = (float*)alloc((size_t)B_ROWS * DZ * 4);      // 4.2 MB
  float*  Wqu  = (float*)alloc((size_t)DZ * DZ * 4);          // 0.26 MB
  float*  e_ws = (float*)alloc((size_t)E_EDGES * 4);          // 0.52 MB

  wqu_kernel<<<256, 256, 0, stream>>>(Wv, Wu, Wqu);
  u_kernel<<<B_ROWS / 16, 256, 0, stream>>>(Zs, Wqu, u_ws);
  cvt_bf16<<<(HD4 * DPAIR / 4 + 255) / 256, 256, 0, stream>>>(
      (const float4*)W1, (ushort4*)W1b, HD4 * DPAIR / 4);
  cvt_bf16<<<(NOUT * HD4 / 4 + 255) / 256, 256, 0, stream>>>(
      (const float4*)W2, (ushort4*)W2b, NOUT * HD4 / 4);
  attn_agg<<<B_ROWS, 256, 0, stream>>>(Zn, Ep, u_ws, ptr, e_ws,
                                       (__hip_bfloat16*)EvXb);
  gemm_bt<1><<<(B_ROWS / 128) * (HD4 / 128), 256, 0, stream>>>(
      EvXb, W1b, b1, hdn, B_ROWS, HD4, DPAIR);
  gemm_bt<0><<<(B_ROWS / 128) * (NOUT / 128), 256, 0, stream>>>(
      hdn, W2b, b2, out, B_ROWS, NOUT, HD4);
}